// Round 3
// baseline (340.893 us; speedup 1.0000x reference)
//
#include <hip/hip_runtime.h>
#include <math.h>

// GCN 2-layer, N=100000, E=3200000, feats 2->16->2.
// R10: attack the wave-supply problem R9's counters exposed (aggc: occ 24%,
// HBM 3.9%, VALU 1.5% = one resident block per CU, pure serial latency).
//  (a) k_deg DELETED: degree folded into k_pass1 as fire-and-forget global
//      atomicAdd(&deg[dst],1) (3.2M int atomics, ~32/address, contention-free;
//      dst already in registers). Saves a full ~45us slotsC pass.
//  (b) agg chunks 8192->4096 edges, 512 thr (EPT=8): 833 blocks instead of 441
//      -> 3.25 blocks/CU supplied, 4 co-resident (LDS 16KB, thr 2048) so block
//      phases overlap. Partials grow to 49*17 rows (13.6MB/layer r+w = noise).
//  (c) pass1 chunks 8192->4096: 782 blocks, occupancy cap 38%->76%.
// Structure otherwise as R9: one coarse radix level (49 buckets x 2048 nodes),
// per-(bucket,chunk) LDS accumulate -> coalesced non-atomic partials ->
// per-node combine (dinv / fused MLP / log_softmax).

constexpr int N = 100000;
constexpr int NC = 49;        // coarse buckets (dst>>11)
constexpr int CB = 2048;      // nodes per coarse bucket
constexpr int CAP1 = 68608;   // coarse cap: mean 65306 + ~13 sigma

constexpr int B1 = 512;       // pass1 block
constexpr int EC1 = 4096;     // pass1 edges/chunk
constexpr int EPT1 = EC1 / B1;  // 8

constexpr int BA = 512;       // agg block
constexpr int ECA = 4096;     // agg edges/chunk
constexpr int EPTA = ECA / BA;  // 8
constexpr int MAXCHA = (CAP1 + ECA - 1) / ECA;  // 17 chunks per bucket

__global__ __launch_bounds__(B1) void k_pass1(const int* __restrict__ src,
                                              const int* __restrict__ dst, int E,
                                              int* __restrict__ gfill1,
                                              int* __restrict__ deg,
                                              int* __restrict__ slotsC) {
    __shared__ int hist[NC];
    __shared__ int base[NC];
    int t = threadIdx.x;
    if (t < NC) hist[t] = 0;
    __syncthreads();
    int s[EPT1], d[EPT1];
    int ebase = blockIdx.x * EC1 + t * EPT1;
#pragma unroll
    for (int k = 0; k < EPT1 / 4; k++) {
        int idx = ebase + 4 * k;
        if (idx + 3 < E) {
            *(int4*)(s + 4 * k) = *(const int4*)(src + idx);
            *(int4*)(d + 4 * k) = *(const int4*)(dst + idx);
        } else {
            for (int j = 0; j < 4; j++) {
                s[4 * k + j] = (idx + j < E) ? src[idx + j] : -1;
                d[4 * k + j] = (idx + j < E) ? dst[idx + j] : -1;
            }
        }
    }
#pragma unroll
    for (int k = 0; k < EPT1; k++)
        if (d[k] >= 0) {
            atomicAdd(&hist[d[k] >> 11], 1);  // LDS coarse hist
            atomicAdd(&deg[d[k]], 1);         // global degree, fire-and-forget
        }
    __syncthreads();
    if (t < NC) {
        int c = hist[t];
        base[t] = c ? atomicAdd(&gfill1[t], c) : 0;  // device reservation atomic
        hist[t] = 0;                                  // reuse as cursor
    }
    __syncthreads();
#pragma unroll
    for (int k = 0; k < EPT1; k++) {
        if (d[k] >= 0) {
            int bin = d[k] >> 11;
            int r = atomicAdd(&hist[bin], 1);  // LDS
            int pos = base[bin] + r;
            if (pos < CAP1) slotsC[bin * CAP1 + pos] = (s[k] << 11) | (d[k] & 2047);
        }
    }
}

// per node: dinv = rsqrt(deg+1); sx = x*dinv
__global__ __launch_bounds__(256) void k_dinv(const int* __restrict__ deg,
                                              const float* __restrict__ x,
                                              float* __restrict__ dinv,
                                              float2* __restrict__ sx) {
    int node = blockIdx.x * 256 + threadIdx.x;
    if (node >= N) return;
    float di = rsqrtf((float)(deg[node] + 1));
    dinv[node] = di;
    float2 xv = ((const float2*)x)[node];
    sx[node] = make_float2(xv.x * di, xv.y * di);
}

// per-(bucket,chunk) aggregate: gather vals[src], LDS acc over 2048 local dst,
// write coalesced non-atomic partials.
__global__ __launch_bounds__(BA) void k_aggc(const int* __restrict__ gfill1,
                                             const int* __restrict__ slotsC,
                                             const float2* __restrict__ vals,
                                             float* __restrict__ partX,
                                             float* __restrict__ partY) {
    __shared__ float aX[CB], aY[CB];
    int c = blockIdx.x / MAXCHA, j = blockIdx.x % MAXCHA;
    int fill = min(gfill1[c], CAP1);
    int e0 = j * ECA;
    if (e0 >= fill) return;  // uniform per block, before any sync
    int e1 = min(fill, e0 + ECA);
    int t = threadIdx.x;
    for (int i = t; i < CB; i += BA) { aX[i] = 0.f; aY[i] = 0.f; }
    __syncthreads();
    const int* row = slotsC + c * CAP1;
    int v[EPTA];
    int ebase = e0 + t * EPTA;
#pragma unroll
    for (int k = 0; k < EPTA / 4; k++) {
        int idx = ebase + 4 * k;
        if (idx + 3 < e1) {
            *(int4*)(v + 4 * k) = *(const int4*)(row + idx);
        } else {
            for (int jj = 0; jj < 4; jj++) v[4 * k + jj] = (idx + jj < e1) ? row[idx + jj] : -1;
        }
    }
    // independent gathers issued before any atomic
    float2 g[EPTA];
#pragma unroll
    for (int k = 0; k < EPTA; k++) g[k] = (v[k] >= 0) ? vals[v[k] >> 11] : make_float2(0.f, 0.f);
#pragma unroll
    for (int k = 0; k < EPTA; k++) {
        if (v[k] >= 0) {
            int d = v[k] & (CB - 1);
            atomicAdd(&aX[d], g[k].x);
            atomicAdd(&aY[d], g[k].y);
        }
    }
    __syncthreads();
    float* px = partX + blockIdx.x * CB;
    float* py = partY + blockIdx.x * CB;
    for (int i = t; i < CB; i += BA) { px[i] = aX[i]; py[i] = aY[i]; }
}

// combine layer1 partials + self, *di, fused MLP; sz = (h@W2)*di
__global__ __launch_bounds__(256) void k_comb1(const int* __restrict__ gfill1,
                                               const float* __restrict__ partX,
                                               const float* __restrict__ partY,
                                               const float* __restrict__ dinv,
                                               const float2* __restrict__ sx,
                                               const float* __restrict__ W1,
                                               const float* __restrict__ b1,
                                               const float* __restrict__ W2,
                                               float2* __restrict__ sz) {
    __shared__ float sW1[32], sb1[16], sW2[32];
    int t = threadIdx.x;
    if (t < 32) sW1[t] = W1[t];
    else if (t < 48) sb1[t - 32] = b1[t - 32];
    else if (t < 80) sW2[t - 48] = W2[t - 48];
    __syncthreads();
    int node = blockIdx.x * 256 + t;
    if (node >= N) return;
    int c = node >> 11, i = node & (CB - 1);
    int nch = (min(gfill1[c], CAP1) + ECA - 1) / ECA;
    const float* px = partX + (size_t)c * MAXCHA * CB + i;
    const float* py = partY + (size_t)c * MAXCHA * CB + i;
    float ax = 0.f, ay = 0.f;
    for (int j = 0; j < nch; j++) { ax += px[j * CB]; ay += py[j * CB]; }
    float di = dinv[node];
    float2 sv = sx[node];
    float a0 = (ax + sv.x) * di;
    float a1 = (ay + sv.y) * di;
    float z0 = 0.f, z1 = 0.f;
#pragma unroll
    for (int k = 0; k < 16; k++) {
        float h = fmaf(a0, sW1[k], fmaf(a1, sW1[16 + k], sb1[k]));
        h = fmaxf(h, 0.f);
        z0 = fmaf(h, sW2[2 * k + 0], z0);
        z1 = fmaf(h, sW2[2 * k + 1], z1);
    }
    sz[node] = make_float2(z0 * di, z1 * di);
}

// combine layer2 partials + self, *di, + bias, log_softmax
__global__ __launch_bounds__(256) void k_comb2(const int* __restrict__ gfill1,
                                               const float* __restrict__ partX,
                                               const float* __restrict__ partY,
                                               const float* __restrict__ dinv,
                                               const float2* __restrict__ sz,
                                               const float* __restrict__ b2,
                                               float2* __restrict__ out) {
    int node = blockIdx.x * 256 + threadIdx.x;
    if (node >= N) return;
    int c = node >> 11, i = node & (CB - 1);
    int nch = (min(gfill1[c], CAP1) + ECA - 1) / ECA;
    const float* px = partX + (size_t)c * MAXCHA * CB + i;
    const float* py = partY + (size_t)c * MAXCHA * CB + i;
    float ax = 0.f, ay = 0.f;
    for (int j = 0; j < nch; j++) { ax += px[j * CB]; ay += py[j * CB]; }
    float di = dinv[node];
    float2 sv = sz[node];
    float v0 = fmaf(ax + sv.x, di, b2[0]);
    float v1 = fmaf(ay + sv.y, di, b2[1]);
    float m = fmaxf(v0, v1);
    float lse = m + logf(expf(v0 - m) + expf(v1 - m));
    out[node] = make_float2(v0 - lse, v1 - lse);
}

extern "C" void kernel_launch(void* const* d_in, const int* in_sizes, int n_in,
                              void* d_out, int out_size, void* d_ws, size_t ws_size,
                              hipStream_t stream) {
    const float* x  = (const float*)d_in[0];
    const int*   ei = (const int*)d_in[1];
    const float* W1 = (const float*)d_in[2];
    const float* b1 = (const float*)d_in[3];
    const float* W2 = (const float*)d_in[4];
    const float* b2 = (const float*)d_in[5];

    const int E = in_sizes[1] / 2;
    const int* src = ei;
    const int* dst = ei + E;
    const int GP = (E + EC1 - 1) / EC1;    // 782 pass1 blocks
    const int GB = NC * MAXCHA;            // 833 agg chunk blocks
    const int GN = (N + 255) / 256;        // 391 node blocks

    char* ws = (char*)d_ws;
    size_t off = 0;
    auto alloc = [&](size_t bytes) {
        char* p = ws + off;
        off += (bytes + 511) & ~size_t(511);
        return p;
    };
    // gfill1 + deg contiguous so one memset clears both
    int*    gfill1 = (int*)alloc((64 + N) * sizeof(int));
    int*    deg    = gfill1 + 64;
    float*  dinv   = (float*)alloc(N * sizeof(float));
    float2* sx     = (float2*)alloc(N * sizeof(float2));
    float2* sz     = (float2*)alloc(N * sizeof(float2));
    int*    slotsC = (int*)alloc((size_t)NC * CAP1 * sizeof(int));        // 13.4 MB
    float*  partX  = (float*)alloc((size_t)GB * CB * sizeof(float));      // 6.8 MB
    float*  partY  = (float*)alloc((size_t)GB * CB * sizeof(float));      // 6.8 MB

    hipMemsetAsync(gfill1, 0, (64 + N) * sizeof(int), stream);

    k_pass1<<<GP, B1, 0, stream>>>(src, dst, E, gfill1, deg, slotsC);
    k_dinv<<<GN, 256, 0, stream>>>(deg, x, dinv, sx);
    k_aggc<<<GB, BA, 0, stream>>>(gfill1, slotsC, sx, partX, partY);
    k_comb1<<<GN, 256, 0, stream>>>(gfill1, partX, partY, dinv, sx, W1, b1, W2, sz);
    k_aggc<<<GB, BA, 0, stream>>>(gfill1, slotsC, sz, partX, partY);
    k_comb2<<<GN, 256, 0, stream>>>(gfill1, partX, partY, dinv, sz, b2, (float2*)d_out);
}

// Round 4
// 214.728 us; speedup vs baseline: 1.5876x; 1.5876x over previous
//
#include <hip/hip_runtime.h>
#include <math.h>

// GCN 2-layer, N=100000, E=3200000, feats 2->16->2.
// R11: (a) REVERT R10's global degree atomics (pass1 WRITE_SIZE 113MB, dur
//      147us: device-scope atomics execute past the per-XCD L2 at the
//      memory-side coherence point -> ~32-64B of fabric traffic per 4B atomic).
//      Degree goes back to an LDS-histogram walk over partitioned edges.
//      (b) R9 diagnosis: chunk-walk kernels are gather-CONCURRENCY-bound
//      (441 blocks = 1.7/CU = ~14 waves -> too few outstanding L2 requests).
//      Fix: CB=1024 nodes/bucket (NC=98), 2048-edge chunks, 256-thr blocks ->
//      1764 blocks (~6.9/CU, LDS 8KB, occupancy cap 100%). sx (800KB) is
//      L2-resident; with ~26 waves/CU the gather stream runs at L2 rate.
// Pipeline: k_pass1 (edges -> 98 buckets, packed (src<<10|dstLocal), 8192-edge
//           chunks), k_deg (1024-bin LDS hist -> partials), k_dinv,
//           k_aggc (gather sx[src] -> LDS acc[1024] -> partials),
//           k_comb1 (sum + MLP -> sz), k_aggc over sz, k_comb2 (softmax).

constexpr int N = 100000;
constexpr int LOGCB = 10;
constexpr int CB = 1 << LOGCB;   // 1024 nodes per bucket
constexpr int NC = 98;           // buckets (dst>>10)
constexpr int CAP1 = 35008;      // cap: mean 32768 + ~12 sigma (64-mult)

constexpr int B1 = 512;          // pass1 block
constexpr int EC1 = 8192;        // pass1 edges/chunk
constexpr int EPT1 = EC1 / B1;   // 16

constexpr int BA = 256;          // walk block (deg/agg)
constexpr int ECA = 2048;        // walk edges/chunk
constexpr int EPTA = ECA / BA;   // 8
constexpr int MAXCH = (CAP1 + ECA - 1) / ECA;  // 18 chunks per bucket

__global__ __launch_bounds__(B1) void k_pass1(const int* __restrict__ src,
                                              const int* __restrict__ dst, int E,
                                              int* __restrict__ gfill1,
                                              int* __restrict__ slotsC) {
    __shared__ int hist[NC];
    __shared__ int base[NC];
    int t = threadIdx.x;
    if (t < NC) hist[t] = 0;
    __syncthreads();
    int s[EPT1], d[EPT1];
    int ebase = blockIdx.x * EC1 + t * EPT1;
#pragma unroll
    for (int k = 0; k < EPT1 / 4; k++) {
        int idx = ebase + 4 * k;
        if (idx + 3 < E) {
            *(int4*)(s + 4 * k) = *(const int4*)(src + idx);
            *(int4*)(d + 4 * k) = *(const int4*)(dst + idx);
        } else {
            for (int j = 0; j < 4; j++) {
                s[4 * k + j] = (idx + j < E) ? src[idx + j] : -1;
                d[4 * k + j] = (idx + j < E) ? dst[idx + j] : -1;
            }
        }
    }
#pragma unroll
    for (int k = 0; k < EPT1; k++)
        if (d[k] >= 0) atomicAdd(&hist[d[k] >> LOGCB], 1);
    __syncthreads();
    if (t < NC) {
        int c = hist[t];
        base[t] = c ? atomicAdd(&gfill1[t], c) : 0;  // device reservation atomic
        hist[t] = 0;                                  // reuse as cursor
    }
    __syncthreads();
#pragma unroll
    for (int k = 0; k < EPT1; k++) {
        if (d[k] >= 0) {
            int bin = d[k] >> LOGCB;
            int r = atomicAdd(&hist[bin], 1);  // LDS
            int pos = base[bin] + r;
            if (pos < CAP1) slotsC[bin * CAP1 + pos] = (s[k] << LOGCB) | (d[k] & (CB - 1));
        }
    }
}

// per-(bucket,chunk) degree histogram -> coalesced non-atomic partials
__global__ __launch_bounds__(BA) void k_deg(const int* __restrict__ gfill1,
                                            const int* __restrict__ slotsC,
                                            int* __restrict__ degPart) {
    __shared__ int dh[CB];
    int c = blockIdx.x / MAXCH, j = blockIdx.x % MAXCH;
    int fill = min(gfill1[c], CAP1);
    int e0 = j * ECA;
    if (e0 >= fill) return;  // uniform per block, before any sync
    int e1 = min(fill, e0 + ECA);
    int t = threadIdx.x;
    for (int i = t; i < CB; i += BA) dh[i] = 0;
    __syncthreads();
    const int* row = slotsC + c * CAP1;
    int v[EPTA];
    int ebase = e0 + t * EPTA;
#pragma unroll
    for (int k = 0; k < EPTA / 4; k++) {
        int idx = ebase + 4 * k;
        if (idx + 3 < e1) {
            *(int4*)(v + 4 * k) = *(const int4*)(row + idx);
        } else {
            for (int jj = 0; jj < 4; jj++) v[4 * k + jj] = (idx + jj < e1) ? row[idx + jj] : -1;
        }
    }
#pragma unroll
    for (int k = 0; k < EPTA; k++)
        if (v[k] >= 0) atomicAdd(&dh[v[k] & (CB - 1)], 1);
    __syncthreads();
    int* dp = degPart + blockIdx.x * CB;
    for (int i = t; i < CB; i += BA) dp[i] = dh[i];
}

// per node: deg = sum of nch chunk partials; dinv = rsqrt(deg+1); sx = x*dinv
__global__ __launch_bounds__(256) void k_dinv(const int* __restrict__ gfill1,
                                              const int* __restrict__ degPart,
                                              const float* __restrict__ x,
                                              float* __restrict__ dinv,
                                              float2* __restrict__ sx) {
    int node = blockIdx.x * 256 + threadIdx.x;
    if (node >= N) return;
    int c = node >> LOGCB, i = node & (CB - 1);
    int nch = (min(gfill1[c], CAP1) + ECA - 1) / ECA;
    const int* p = degPart + (size_t)c * MAXCH * CB + i;
    int deg = 0;
    for (int j = 0; j < nch; j++) deg += p[j * CB];
    float di = rsqrtf((float)(deg + 1));
    dinv[node] = di;
    float2 xv = ((const float2*)x)[node];
    sx[node] = make_float2(xv.x * di, xv.y * di);
}

// per-(bucket,chunk) aggregate: gather vals[src] (L2-resident), LDS acc over
// 1024 local dst, write coalesced non-atomic partials.
__global__ __launch_bounds__(BA) void k_aggc(const int* __restrict__ gfill1,
                                             const int* __restrict__ slotsC,
                                             const float2* __restrict__ vals,
                                             float* __restrict__ partX,
                                             float* __restrict__ partY) {
    __shared__ float aX[CB], aY[CB];
    int c = blockIdx.x / MAXCH, j = blockIdx.x % MAXCH;
    int fill = min(gfill1[c], CAP1);
    int e0 = j * ECA;
    if (e0 >= fill) return;  // uniform per block, before any sync
    int e1 = min(fill, e0 + ECA);
    int t = threadIdx.x;
    for (int i = t; i < CB; i += BA) { aX[i] = 0.f; aY[i] = 0.f; }
    __syncthreads();
    const int* row = slotsC + c * CAP1;
    int v[EPTA];
    int ebase = e0 + t * EPTA;
#pragma unroll
    for (int k = 0; k < EPTA / 4; k++) {
        int idx = ebase + 4 * k;
        if (idx + 3 < e1) {
            *(int4*)(v + 4 * k) = *(const int4*)(row + idx);
        } else {
            for (int jj = 0; jj < 4; jj++) v[4 * k + jj] = (idx + jj < e1) ? row[idx + jj] : -1;
        }
    }
    // all gathers issued before any atomic (max outstanding per wave)
    float2 g[EPTA];
#pragma unroll
    for (int k = 0; k < EPTA; k++) g[k] = (v[k] >= 0) ? vals[v[k] >> LOGCB] : make_float2(0.f, 0.f);
#pragma unroll
    for (int k = 0; k < EPTA; k++) {
        if (v[k] >= 0) {
            int d = v[k] & (CB - 1);
            atomicAdd(&aX[d], g[k].x);
            atomicAdd(&aY[d], g[k].y);
        }
    }
    __syncthreads();
    float* px = partX + blockIdx.x * CB;
    float* py = partY + blockIdx.x * CB;
    for (int i = t; i < CB; i += BA) { px[i] = aX[i]; py[i] = aY[i]; }
}

// combine layer1 partials + self, *di, fused MLP; sz = (h@W2)*di
__global__ __launch_bounds__(256) void k_comb1(const int* __restrict__ gfill1,
                                               const float* __restrict__ partX,
                                               const float* __restrict__ partY,
                                               const float* __restrict__ dinv,
                                               const float2* __restrict__ sx,
                                               const float* __restrict__ W1,
                                               const float* __restrict__ b1,
                                               const float* __restrict__ W2,
                                               float2* __restrict__ sz) {
    __shared__ float sW1[32], sb1[16], sW2[32];
    int t = threadIdx.x;
    if (t < 32) sW1[t] = W1[t];
    else if (t < 48) sb1[t - 32] = b1[t - 32];
    else if (t < 80) sW2[t - 48] = W2[t - 48];
    __syncthreads();
    int node = blockIdx.x * 256 + t;
    if (node >= N) return;
    int c = node >> LOGCB, i = node & (CB - 1);
    int nch = (min(gfill1[c], CAP1) + ECA - 1) / ECA;
    const float* px = partX + (size_t)c * MAXCH * CB + i;
    const float* py = partY + (size_t)c * MAXCH * CB + i;
    float ax = 0.f, ay = 0.f;
    for (int j = 0; j < nch; j++) { ax += px[j * CB]; ay += py[j * CB]; }
    float di = dinv[node];
    float2 sv = sx[node];
    float a0 = (ax + sv.x) * di;
    float a1 = (ay + sv.y) * di;
    float z0 = 0.f, z1 = 0.f;
#pragma unroll
    for (int k = 0; k < 16; k++) {
        float h = fmaf(a0, sW1[k], fmaf(a1, sW1[16 + k], sb1[k]));
        h = fmaxf(h, 0.f);
        z0 = fmaf(h, sW2[2 * k + 0], z0);
        z1 = fmaf(h, sW2[2 * k + 1], z1);
    }
    sz[node] = make_float2(z0 * di, z1 * di);
}

// combine layer2 partials + self, *di, + bias, log_softmax
__global__ __launch_bounds__(256) void k_comb2(const int* __restrict__ gfill1,
                                               const float* __restrict__ partX,
                                               const float* __restrict__ partY,
                                               const float* __restrict__ dinv,
                                               const float2* __restrict__ sz,
                                               const float* __restrict__ b2,
                                               float2* __restrict__ out) {
    int node = blockIdx.x * 256 + threadIdx.x;
    if (node >= N) return;
    int c = node >> LOGCB, i = node & (CB - 1);
    int nch = (min(gfill1[c], CAP1) + ECA - 1) / ECA;
    const float* px = partX + (size_t)c * MAXCH * CB + i;
    const float* py = partY + (size_t)c * MAXCH * CB + i;
    float ax = 0.f, ay = 0.f;
    for (int j = 0; j < nch; j++) { ax += px[j * CB]; ay += py[j * CB]; }
    float di = dinv[node];
    float2 sv = sz[node];
    float v0 = fmaf(ax + sv.x, di, b2[0]);
    float v1 = fmaf(ay + sv.y, di, b2[1]);
    float m = fmaxf(v0, v1);
    float lse = m + logf(expf(v0 - m) + expf(v1 - m));
    out[node] = make_float2(v0 - lse, v1 - lse);
}

extern "C" void kernel_launch(void* const* d_in, const int* in_sizes, int n_in,
                              void* d_out, int out_size, void* d_ws, size_t ws_size,
                              hipStream_t stream) {
    const float* x  = (const float*)d_in[0];
    const int*   ei = (const int*)d_in[1];
    const float* W1 = (const float*)d_in[2];
    const float* b1 = (const float*)d_in[3];
    const float* W2 = (const float*)d_in[4];
    const float* b2 = (const float*)d_in[5];

    const int E = in_sizes[1] / 2;
    const int* src = ei;
    const int* dst = ei + E;
    const int GP = (E + EC1 - 1) / EC1;   // 391 pass1 blocks
    const int GB = NC * MAXCH;            // 1764 walk blocks
    const int GN = (N + 255) / 256;       // 391 node blocks

    char* ws = (char*)d_ws;
    size_t off = 0;
    auto alloc = [&](size_t bytes) {
        char* p = ws + off;
        off += (bytes + 511) & ~size_t(511);
        return p;
    };
    int*    gfill1  = (int*)alloc(128 * sizeof(int));
    float*  dinv    = (float*)alloc(N * sizeof(float));
    float2* sx      = (float2*)alloc(N * sizeof(float2));
    float2* sz      = (float2*)alloc(N * sizeof(float2));
    int*    slotsC  = (int*)alloc((size_t)NC * CAP1 * sizeof(int));     // 13.7 MB
    int*    degPart = (int*)alloc((size_t)GB * CB * sizeof(int));       // 7.2 MB
    float*  partX   = (float*)alloc((size_t)GB * CB * sizeof(float));   // 7.2 MB
    float*  partY   = (float*)alloc((size_t)GB * CB * sizeof(float));   // 7.2 MB

    hipMemsetAsync(gfill1, 0, 128 * sizeof(int), stream);

    k_pass1<<<GP, B1, 0, stream>>>(src, dst, E, gfill1, slotsC);
    k_deg<<<GB, BA, 0, stream>>>(gfill1, slotsC, degPart);
    k_dinv<<<GN, 256, 0, stream>>>(gfill1, degPart, x, dinv, sx);
    k_aggc<<<GB, BA, 0, stream>>>(gfill1, slotsC, sx, partX, partY);
    k_comb1<<<GN, 256, 0, stream>>>(gfill1, partX, partY, dinv, sx, W1, b1, W2, sz);
    k_aggc<<<GB, BA, 0, stream>>>(gfill1, slotsC, sz, partX, partY);
    k_comb2<<<GN, 256, 0, stream>>>(gfill1, partX, partY, dinv, sz, b2, (float2*)d_out);
}